// Round 4
// baseline (415.778 us; speedup 1.0000x reference)
//
#include <hip/hip_runtime.h>
#include <hip/hip_bf16.h>

typedef _Float16 f16x8 __attribute__((ext_vector_type(8)));
typedef _Float16 f16x4 __attribute__((ext_vector_type(4)));
typedef float f32x4 __attribute__((ext_vector_type(4)));

#define B_SZ 64
#define T_SZ 2048
#define D_SZ 300
#define M_SZ (B_SZ * T_SZ)      // 131072
#define KP 320                   // padded K for W
#define NP 640                   // padded combined N (z: 0..299, o: 320..619)
#define NCHUNK 32
#define CLEN 64                  // T / NCHUNK

__device__ __forceinline__ float fast_tanh(float x) {
    float e = __expf(2.0f * x);
    return 1.0f - 2.0f * __builtin_amdgcn_rcpf(e + 1.0f);
}

// ---- pack Wz/Wo fp32 [300,300] -> combined fp16 [640,320], zero-padded ----
__global__ void pack_w(const float* __restrict__ Wz, const float* __restrict__ Wo,
                       _Float16* __restrict__ W) {
    unsigned int i = blockIdx.x * 256u + threadIdx.x;
    if (i >= NP * KP) return;
    unsigned int n = i / KP;
    unsigned int k = i - n * KP;
    float v = 0.0f;
    if (k < D_SZ) {
        if (n < D_SZ) v = Wz[n * D_SZ + k];
        else if (n >= 320 && n < 320 + D_SZ) v = Wo[(n - 320) * D_SZ + k];
    }
    W[i] = (_Float16)v;
}

__global__ void pack_bias(const float* __restrict__ bz, const float* __restrict__ bo,
                          float* __restrict__ bias) {
    int n = threadIdx.x;
    float v = 0.0f;
    if (n < D_SZ) v = bz[n];
    else if (n >= 320 && n < 320 + D_SZ) v = bo[n - 320];
    bias[n] = v;
}

__device__ __forceinline__ f16x8 cvt8(f32x4 v0, f32x4 v1) {
    f16x8 r;
    r[0] = (_Float16)v0[0]; r[1] = (_Float16)v0[1];
    r[2] = (_Float16)v0[2]; r[3] = (_Float16)v0[3];
    r[4] = (_Float16)v1[0]; r[5] = (_Float16)v1[1];
    r[6] = (_Float16)v1[2]; r[7] = (_Float16)v1[3];
    return r;
}

// Load 8 k-values of A (fp32 -> fp16) at p (already offset by row*300 + kq*8 + kt*32).
// tail=true for kt==9 (k base 288): guard OOB; W zeros make the masked lanes moot.
__device__ __forceinline__ f16x8 loadA(const float* __restrict__ p, bool tail, int kq) {
    f32x4 v0 = {}, v1 = {};
    if (!tail) {
        v0 = *(const f32x4*)p;
        v1 = *(const f32x4*)(p + 4);
    } else {
        if (kq < 2) v0 = *(const f32x4*)p;          // k 288..291 / 296..299
        if (kq < 1) v1 = *(const f32x4*)(p + 4);    // k 292..295
    }
    return cvt8(v0, v1);
}

// ---- GEMM: C16[m][n] = tanh( sum_k X[m][k]*W[n][k] + bias[n] ), fp16 out ----
// LDS-free: MFMA fragments loaded straight from global (X fp32 -> cvt, W fp16
// L2-resident). No barriers; compiler pipelines the flat load/MFMA stream.
// 128x128 block tile, 4 waves (2x2), each wave 64x64 via 16x16x32 f16 MFMA.
__global__ __launch_bounds__(256) void gemm_zo(const float* __restrict__ X,
                                               const _Float16* __restrict__ W,
                                               const float* __restrict__ bias,
                                               _Float16* __restrict__ C) {
    const int lane = threadIdx.x & 63;
    const int wid = threadIdx.x >> 6;      // 0..3
    const int wm = wid >> 1, wn = wid & 1;

    // XCD-aware swizzle (5120 blocks, 5120 % 8 == 0 -> bijective)
    int g = blockIdx.x;
    int s = (g & 7) * (5120 / 8) + (g >> 3);
    int bm = s / 5;          // 1024 M-tiles
    int bn = s - bm * 5;     // 5 N-tiles

    const int l15 = lane & 15;
    const int kq = lane >> 4;              // k-quad 0..3

    const float* ap[4];
    const _Float16* bp[4];
#pragma unroll
    for (int ms = 0; ms < 4; ++ms) {
        int row = bm * 128 + wm * 64 + ms * 16 + l15;
        ap[ms] = X + (size_t)row * D_SZ + kq * 8;
    }
#pragma unroll
    for (int ns = 0; ns < 4; ++ns) {
        int row = bn * 128 + wn * 64 + ns * 16 + l15;
        bp[ns] = W + (size_t)row * KP + kq * 8;
    }

    f32x4 acc[4][4] = {};

    f16x8 ac[4], bc[4];
#pragma unroll
    for (int ms = 0; ms < 4; ++ms) ac[ms] = loadA(ap[ms], false, kq);
#pragma unroll
    for (int ns = 0; ns < 4; ++ns) bc[ns] = *(const f16x8*)(bp[ns]);

#pragma unroll 2
    for (int kt = 0; kt < 10; ++kt) {
        f16x8 an[4], bnx[4];
        if (kt < 9) {
            bool tail = (kt == 8);         // loading kt+1 == 9 (k base 288)
#pragma unroll
            for (int ms = 0; ms < 4; ++ms) an[ms] = loadA(ap[ms] + (kt + 1) * 32, tail, kq);
#pragma unroll
            for (int ns = 0; ns < 4; ++ns) bnx[ns] = *(const f16x8*)(bp[ns] + (kt + 1) * 32);
        }

        __builtin_amdgcn_s_setprio(1);
#pragma unroll
        for (int ms = 0; ms < 4; ++ms)
#pragma unroll
            for (int ns = 0; ns < 4; ++ns)
                acc[ms][ns] = __builtin_amdgcn_mfma_f32_16x16x32_f16(bc[ns], ac[ms], acc[ms][ns], 0, 0, 0);
        __builtin_amdgcn_s_setprio(0);

        if (kt < 9) {
#pragma unroll
            for (int ms = 0; ms < 4; ++ms) ac[ms] = an[ms];
#pragma unroll
            for (int ns = 0; ns < 4; ++ns) bc[ns] = bnx[ns];
        }
    }

    // epilogue: swapped layout -> lane holds 4 consecutive n at one m.
    // m = mrow0 + ms*16 + (lane&15); n = ncol0 + ns*16 + (lane>>4)*4 + r
    const int mrow0 = bm * 128 + wm * 64;
    const int ncol0 = bn * 128 + wn * 64;
#pragma unroll
    for (int ns = 0; ns < 4; ++ns) {
        int nb = ncol0 + ns * 16 + kq * 4;
        f32x4 b4 = *(const f32x4*)&bias[nb];
#pragma unroll
        for (int ms = 0; ms < 4; ++ms) {
            int m = mrow0 + ms * 16 + l15;
            f16x4 v;
#pragma unroll
            for (int r = 0; r < 4; ++r)
                v[r] = (_Float16)fast_tanh(acc[ms][ns][r] + b4[r]);
            *(f16x4*)&C[(size_t)m * NP + nb] = v;
        }
    }
}

// ---- scan phase 1: per (b, chunk, d) compute affine (A = prod g, Bc) ----
__global__ void scan_p1(const float* __restrict__ gate, const _Float16* __restrict__ C,
                        float* __restrict__ Aout, float* __restrict__ Bout) {
    int b = blockIdx.x >> 5;
    int nc = blockIdx.x & 31;
    int d = threadIdx.x;
    if (d >= D_SZ) return;
    size_t base = (size_t)b * T_SZ + (size_t)nc * CLEN;
    const float* gp = gate + base * D_SZ + d;
    const _Float16* zp = C + base * NP + d;
    float A = 1.0f, Bc = 0.0f;
    for (int t = 0; t < CLEN; ++t) {
        float gv = gp[(size_t)t * D_SZ];
        float zv = (float)zp[(size_t)t * NP];
        A *= gv;
        Bc = gv * Bc + (1.0f - gv) * zv;
    }
    int o = (b * NCHUNK + nc) * D_SZ + d;
    Aout[o] = A;
    Bout[o] = Bc;
}

// ---- scan phase 2: sequential scan over the 32 chunk summaries ----
__global__ void scan_p2(const float* __restrict__ A, const float* __restrict__ Bc,
                        float* __restrict__ Cin) {
    int idx = blockIdx.x * 256 + threadIdx.x;
    if (idx >= B_SZ * D_SZ) return;
    int b = idx / D_SZ;
    int d = idx - b * D_SZ;
    float c = 0.0f;
    for (int nc = 0; nc < NCHUNK; ++nc) {
        int o = (b * NCHUNK + nc) * D_SZ + d;
        Cin[o] = c;
        c = A[o] * c + Bc[o];
    }
}

// ---- scan phase 3: replay chunk with correct c_in, write h = o * c ----
__global__ void scan_p3(const float* __restrict__ gate, const _Float16* __restrict__ C,
                        const float* __restrict__ Cin, float* __restrict__ out) {
    int b = blockIdx.x >> 5;
    int nc = blockIdx.x & 31;
    int d = threadIdx.x;
    if (d >= D_SZ) return;
    size_t base = (size_t)b * T_SZ + (size_t)nc * CLEN;
    const float* gp = gate + base * D_SZ + d;
    const _Float16* zp = C + base * NP + d;
    const _Float16* op = zp + 320;
    float* hp = out + base * D_SZ + d;
    float c = Cin[(b * NCHUNK + nc) * D_SZ + d];
    for (int t = 0; t < CLEN; ++t) {
        float gv = gp[(size_t)t * D_SZ];
        float zv = (float)zp[(size_t)t * NP];
        float ov = (float)op[(size_t)t * NP];
        c = gv * c + (1.0f - gv) * zv;
        hp[(size_t)t * D_SZ] = ov * c;
    }
}

extern "C" void kernel_launch(void* const* d_in, const int* in_sizes, int n_in,
                              void* d_out, int out_size, void* d_ws, size_t ws_size,
                              hipStream_t stream) {
    const float* gate = (const float*)d_in[0];
    const float* xin  = (const float*)d_in[1];
    const float* Wz   = (const float*)d_in[2];
    const float* bz   = (const float*)d_in[3];
    const float* Wo   = (const float*)d_in[4];
    const float* bo   = (const float*)d_in[5];
    float* out = (float*)d_out;

    char* ws = (char*)d_ws;
    _Float16* C16  = (_Float16*)(ws);                       // M*NP*2      = 167,772,160
    _Float16* Wc   = (_Float16*)(ws + 167772160ull);        // NP*KP*2     = 409,600
    float*    bias = (float*)   (ws + 168181760ull);        // NP*4        = 2,560
    float*    Ach  = (float*)   (ws + 168184320ull);        // 64*32*300*4 = 2,457,600
    float*    Bch  = (float*)   (ws + 170641920ull);        // 2,457,600
    float*    Cin  = (float*)   (ws + 173099520ull);        // 2,457,600 (end ~167.4MB+)

    pack_w<<<(NP * KP + 255) / 256, 256, 0, stream>>>(Wz, Wo, Wc);
    pack_bias<<<1, NP, 0, stream>>>(bz, bo, bias);

    gemm_zo<<<(M_SZ / 128) * (NP / 128), 256, 0, stream>>>(xin, Wc, bias, C16);

    scan_p1<<<B_SZ * NCHUNK, 320, 0, stream>>>(gate, C16, Ach, Bch);
    scan_p2<<<(B_SZ * D_SZ + 255) / 256, 256, 0, stream>>>(Ach, Bch, Cin);
    scan_p3<<<B_SZ * NCHUNK, 320, 0, stream>>>(gate, C16, Cin, out);
}

// Round 5
// 306.647 us; speedup vs baseline: 1.3559x; 1.3559x over previous
//
#include <hip/hip_runtime.h>
#include <hip/hip_bf16.h>

typedef _Float16 f16x8 __attribute__((ext_vector_type(8)));
typedef _Float16 f16x4 __attribute__((ext_vector_type(4)));
typedef float f32x4 __attribute__((ext_vector_type(4)));

#define B_SZ 64
#define T_SZ 2048
#define D_SZ 300
#define M_SZ (B_SZ * T_SZ)      // 131072
#define KP 320                   // padded K for W
#define NP 640                   // padded combined N (z: 0..299, o: 320..619)
#define NCHUNK 32
#define CLEN 64                  // T / NCHUNK

__device__ __forceinline__ void gld_lds16(const void* g, void* l) {
    __builtin_amdgcn_global_load_lds(
        (const __attribute__((address_space(1))) unsigned int*)g,
        (__attribute__((address_space(3))) unsigned int*)l,
        16, 0, 0);
}

__device__ __forceinline__ float fast_tanh(float x) {
    float e = __expf(2.0f * x);
    return 1.0f - 2.0f * __builtin_amdgcn_rcpf(e + 1.0f);
}

// ---- pack Wz/Wo fp32 [300,300] -> combined fp16 [640,320], zero-padded ----
__global__ void pack_w(const float* __restrict__ Wz, const float* __restrict__ Wo,
                       _Float16* __restrict__ W) {
    unsigned int i = blockIdx.x * 256u + threadIdx.x;
    if (i >= NP * KP) return;
    unsigned int n = i / KP;
    unsigned int k = i - n * KP;
    float v = 0.0f;
    if (k < D_SZ) {
        if (n < D_SZ) v = Wz[n * D_SZ + k];
        else if (n >= 320 && n < 320 + D_SZ) v = Wo[(n - 320) * D_SZ + k];
    }
    W[i] = (_Float16)v;
}

__global__ void pack_bias(const float* __restrict__ bz, const float* __restrict__ bo,
                          float* __restrict__ bias, float* __restrict__ zpad) {
    int n = threadIdx.x;
    float v = 0.0f;
    if (n < D_SZ) v = bz[n];
    else if (n >= 320 && n < 320 + D_SZ) v = bo[n - 320];
    bias[n] = v;
    if (n < 16) zpad[n] = 0.0f;
}

__device__ __forceinline__ f16x8 cvt8(f32x4 v0, f32x4 v1) {
    f16x8 r;
    r[0] = (_Float16)v0[0]; r[1] = (_Float16)v0[1];
    r[2] = (_Float16)v0[2]; r[3] = (_Float16)v0[3];
    r[4] = (_Float16)v1[0]; r[5] = (_Float16)v1[1];
    r[6] = (_Float16)v1[2]; r[7] = (_Float16)v1[3];
    return r;
}

// ---- GEMM: C16[m][n] = tanh( sum_k X[m][k]*W[n][k] + bias[n] ), fp16 out ----
// 128x128 tile, BK=32, 4 waves (2x2). A staged as FP32 directly from the input
// (no pack kernel), converted after ds_read. Epilogue goes through a wave-
// private LDS tile so global stores are fully coalesced 16B/lane (full lines).
__global__ __launch_bounds__(256) void gemm_zo(const float* __restrict__ X,
                                               const _Float16* __restrict__ W,
                                               const float* __restrict__ bias,
                                               const float* __restrict__ zpad,
                                               _Float16* __restrict__ C) {
    __shared__ float    As[2][128 * 32];   // 32 KB fp32 A tile
    __shared__ _Float16 Bs[2][128 * 32];   // 16 KB fp16 B tile

    const int tid = threadIdx.x;
    const int lane = tid & 63;
    const int wid = tid >> 6;              // 0..3
    const int wm = wid >> 1, wn = wid & 1;

    // XCD-aware swizzle (5120 blocks, 5120 % 8 == 0 -> bijective); 5 bn-tiles
    // of one bm stay consecutive on one XCD -> X reuse is L2-resident.
    int g = blockIdx.x;
    int s = (g & 7) * (5120 / 8) + (g >> 3);
    int bm = s / 5;          // 1024 M-tiles
    int bn = s - bm * 5;     // 5 N-tiles

    const int l15 = lane & 15;
    const int kq = lane >> 4;

    f32x4 acc[4][4] = {};

    // A staging: 16 chunks of 8 rows (8 x 128B = 1KB); wave stages 4 chunks.
    const int arow_in = lane >> 3;          // row within 8-row chunk (== lds row & 7)
    const int asrc_u = (lane & 7) ^ arow_in;// pre-swizzled 16B source unit
    // B staging: 8 chunks of 16 rows (16 x 64B = 1KB); wave stages 2 chunks.
    const int brow_in = lane >> 2;
    const int bsrc_u = (lane & 3) ^ ((brow_in >> 1) & 3);

    auto stage = [&](int buf, int kt) {
#pragma unroll
        for (int j = 0; j < 4; ++j) {
            int c = wid * 4 + j;
            int row = c * 8 + arow_in;
            const float* src = (kt == 9 && asrc_u >= 3)
                ? zpad
                : X + (size_t)(bm * 128 + row) * D_SZ + kt * 32 + asrc_u * 4;
            gld_lds16(src, &As[buf][c * 256]);
        }
#pragma unroll
        for (int j = 0; j < 2; ++j) {
            int c = wid + j * 4;
            int row = c * 16 + brow_in;
            gld_lds16(W + (size_t)(bn * 128 + row) * KP + kt * 32 + bsrc_u * 8,
                      &Bs[buf][c * 512]);
        }
    };

    stage(0, 0);
    __syncthreads();

    int buf = 0;
#pragma unroll 1
    for (int kt = 0; kt < 10; ++kt) {
        if (kt < 9) stage(buf ^ 1, kt + 1);

        const int key = l15 & 7;
        f16x8 bf[4], af[4];
#pragma unroll
        for (int ns = 0; ns < 4; ++ns) {
            int row = wn * 64 + ns * 16 + l15;
            int u = kq ^ ((row >> 1) & 3);
            bf[ns] = *(const f16x8*)&Bs[buf][row * 32 + u * 8];
        }
#pragma unroll
        for (int ms = 0; ms < 4; ++ms) {
            int row = wm * 64 + ms * 16 + l15;
            f32x4 lo = *(const f32x4*)&As[buf][row * 32 + ((kq * 2 + 0) ^ key) * 4];
            f32x4 hi = *(const f32x4*)&As[buf][row * 32 + ((kq * 2 + 1) ^ key) * 4];
            af[ms] = cvt8(lo, hi);
        }

        __builtin_amdgcn_s_setprio(1);
#pragma unroll
        for (int ms = 0; ms < 4; ++ms)
#pragma unroll
            for (int ns = 0; ns < 4; ++ns)
                acc[ms][ns] = __builtin_amdgcn_mfma_f32_16x16x32_f16(bf[ns], af[ms], acc[ms][ns], 0, 0, 0);
        __builtin_amdgcn_s_setprio(0);

        __syncthreads();
        buf ^= 1;
    }

    // ---- epilogue: tanh + cvt, LDS shuffle, fully-coalesced 16B stores ----
    // swapped MFMA layout: value (ms,ns,r) at m = mrow0+ms*16+l15,
    //                                     n = ncol0+ns*16+kq*4+r
    const int mrow0 = bm * 128 + wm * 64;
    const int ncol0 = bn * 128 + wn * 64;
    _Float16* et = (_Float16*)&As[0][0] + wid * 1024;   // 16 x 64 f16, wave-private
    const int key = l15 & 7;

    f32x4 b4[4];
#pragma unroll
    for (int ns = 0; ns < 4; ++ns)
        b4[ns] = *(const f32x4*)&bias[ncol0 + ns * 16 + kq * 4];

#pragma unroll
    for (int ms = 0; ms < 4; ++ms) {
#pragma unroll
        for (int ns = 0; ns < 4; ++ns) {
            f16x4 v;
#pragma unroll
            for (int r = 0; r < 4; ++r)
                v[r] = (_Float16)fast_tanh(acc[ms][ns][r] + b4[ns][r]);
            int u = (ns * 2 + (kq >> 1)) ^ key;          // swizzled 16B unit
            *(f16x4*)&et[l15 * 64 + u * 8 + (kq & 1) * 4] = v;
        }
        int m = mrow0 + ms * 16 + l15;
#pragma unroll
        for (int j = 0; j < 2; ++j) {
            int ur = j * 4 + kq;                         // logical 16B unit 0..7
            f16x8 o = *(const f16x8*)&et[l15 * 64 + (ur ^ key) * 8];
            *(f16x8*)&C[(size_t)m * NP + ncol0 + ur * 8] = o;
        }
    }
}

// ---- scan phase 1: per (b, chunk, d) compute affine (A = prod g, Bc) ----
__global__ void scan_p1(const float* __restrict__ gate, const _Float16* __restrict__ C,
                        float* __restrict__ Aout, float* __restrict__ Bout) {
    int b = blockIdx.x >> 5;
    int nc = blockIdx.x & 31;
    int d = threadIdx.x;
    if (d >= D_SZ) return;
    size_t base = (size_t)b * T_SZ + (size_t)nc * CLEN;
    const float* gp = gate + base * D_SZ + d;
    const _Float16* zp = C + base * NP + d;
    float A = 1.0f, Bc = 0.0f;
    for (int t = 0; t < CLEN; ++t) {
        float gv = gp[(size_t)t * D_SZ];
        float zv = (float)zp[(size_t)t * NP];
        A *= gv;
        Bc = gv * Bc + (1.0f - gv) * zv;
    }
    int o = (b * NCHUNK + nc) * D_SZ + d;
    Aout[o] = A;
    Bout[o] = Bc;
}

// ---- scan phase 2: sequential scan over the 32 chunk summaries ----
__global__ void scan_p2(const float* __restrict__ A, const float* __restrict__ Bc,
                        float* __restrict__ Cin) {
    int idx = blockIdx.x * 256 + threadIdx.x;
    if (idx >= B_SZ * D_SZ) return;
    int b = idx / D_SZ;
    int d = idx - b * D_SZ;
    float c = 0.0f;
    for (int nc = 0; nc < NCHUNK; ++nc) {
        int o = (b * NCHUNK + nc) * D_SZ + d;
        Cin[o] = c;
        c = A[o] * c + Bc[o];
    }
}

// ---- scan phase 3: replay chunk with correct c_in, write h = o * c ----
__global__ void scan_p3(const float* __restrict__ gate, const _Float16* __restrict__ C,
                        const float* __restrict__ Cin, float* __restrict__ out) {
    int b = blockIdx.x >> 5;
    int nc = blockIdx.x & 31;
    int d = threadIdx.x;
    if (d >= D_SZ) return;
    size_t base = (size_t)b * T_SZ + (size_t)nc * CLEN;
    const float* gp = gate + base * D_SZ + d;
    const _Float16* zp = C + base * NP + d;
    const _Float16* op = zp + 320;
    float* hp = out + base * D_SZ + d;
    float c = Cin[(b * NCHUNK + nc) * D_SZ + d];
    for (int t = 0; t < CLEN; ++t) {
        float gv = gp[(size_t)t * D_SZ];
        float zv = (float)zp[(size_t)t * NP];
        float ov = (float)op[(size_t)t * NP];
        c = gv * c + (1.0f - gv) * zv;
        hp[(size_t)t * D_SZ] = ov * c;
    }
}

extern "C" void kernel_launch(void* const* d_in, const int* in_sizes, int n_in,
                              void* d_out, int out_size, void* d_ws, size_t ws_size,
                              hipStream_t stream) {
    const float* gate = (const float*)d_in[0];
    const float* xin  = (const float*)d_in[1];
    const float* Wz   = (const float*)d_in[2];
    const float* bz   = (const float*)d_in[3];
    const float* Wo   = (const float*)d_in[4];
    const float* bo   = (const float*)d_in[5];
    float* out = (float*)d_out;

    char* ws = (char*)d_ws;
    _Float16* C16  = (_Float16*)(ws);                       // M*NP*2      = 167,772,160
    _Float16* Wc   = (_Float16*)(ws + 167772160ull);        // NP*KP*2     = 409,600
    float*    bias = (float*)   (ws + 168181760ull);        // NP*4        = 2,560
    float*    zpad = (float*)   (ws + 168184320ull);        // 64 B zero pad
    float*    Ach  = (float*)   (ws + 168184576ull);        // 64*32*300*4 = 2,457,600
    float*    Bch  = (float*)   (ws + 170642176ull);        // 2,457,600
    float*    Cin  = (float*)   (ws + 173099776ull);        // 2,457,600

    pack_w<<<(NP * KP + 255) / 256, 256, 0, stream>>>(Wz, Wo, Wc);
    pack_bias<<<1, NP, 0, stream>>>(bz, bo, bias, zpad);

    gemm_zo<<<(M_SZ / 128) * (NP / 128), 256, 0, stream>>>(xin, Wc, bias, zpad, C16);

    scan_p1<<<B_SZ * NCHUNK, 320, 0, stream>>>(gate, C16, Ach, Bch);
    scan_p2<<<(B_SZ * D_SZ + 255) / 256, 256, 0, stream>>>(Ach, Bch, Cin);
    scan_p3<<<B_SZ * NCHUNK, 320, 0, stream>>>(gate, C16, Cin, out);
}